// Round 2
// baseline (110.848 us; speedup 1.0000x reference)
//
#include <hip/hip_runtime.h>

typedef float f4 __attribute__((ext_vector_type(4)));

#define BB 32
#define CC 64
#define EE 8
#define HWX 4096   // 64*64 pixels
#define PXT 128    // pixels per mix block

// ---------------------------------------------------------------------------
// bf16 helpers (RTNE-ish round via bias add)
// ---------------------------------------------------------------------------
__device__ __forceinline__ unsigned bf16r(float f) {
  unsigned u = __builtin_bit_cast(unsigned, f);
  u += 0x7FFFu + ((u >> 16) & 1u);
  return u >> 16;
}
__device__ __forceinline__ unsigned pack2(float a, float b) {
  return bf16r(a) | (bf16r(b) << 16);
}
__device__ __forceinline__ float ubf_lo(unsigned u) {
  return __builtin_bit_cast(float, u << 16);
}
__device__ __forceinline__ float ubf_hi(unsigned u) {
  return __builtin_bit_cast(float, u & 0xFFFF0000u);
}

// ---------------------------------------------------------------------------
// Kernel A: per-(b,c) plane reductions -> per-c gating partials (no atomics)
// gpart[b][e][c] = sum_{i,j} gw[e,c,i,j] * S[b,c,i,j]
// S[i,j] = T - excludedRows(i) - excludedCols(j) + corners(i,j)
// ---------------------------------------------------------------------------
__global__ __launch_bounds__(256) void k_gate_sums(
    const float* __restrict__ x, const float* __restrict__ gate_w,
    float* __restrict__ gpart) {
  __shared__ float sg[9];       // [T, r0,r1,r62,r63, c0,c1,c62,c63]
  __shared__ float cor[4][4];   // corner cells, rows/cols in {0,1,62,63}
  __shared__ float sS[9];       // the 9 window sums S[i*3+j]
  int t = threadIdx.x;
  int bc = blockIdx.x;          // b*64 + c
  int c = bc & 63;
  const float* plane = x + (size_t)bc * HWX;
  int h = t >> 2, q = t & 3;    // row h (0..63), quarter q (16 floats each)
  const f4* rp = (const f4*)(plane + h * 64 + q * 16);
  f4 a0 = rp[0], a1 = rp[1], a2 = rp[2], a3 = rp[3];
  float local = (a0[0]+a0[1]+a0[2]+a0[3]) + (a1[0]+a1[1]+a1[2]+a1[3])
              + (a2[0]+a2[1]+a2[2]+a2[3]) + (a3[0]+a3[1]+a3[2]+a3[3]);
  if (t < 9) sg[t] = 0.f;
  __syncthreads();

  bool special = (h < 2) || (h >= 62);
  int ridx = (h < 2) ? h : h - 60;   // 0,1,62,63 -> 0,1,2,3

  // wave-reduce the total, one LDS atomic per wave
  float red = local;
  #pragma unroll
  for (int off = 32; off > 0; off >>= 1) red += __shfl_down(red, off, 64);
  if ((t & 63) == 0) atomicAdd(&sg[0], red);

  if (special) atomicAdd(&sg[1 + ridx], local);          // full-row sums
  if (q == 0) {                                          // cols 0,1
    atomicAdd(&sg[5], a0[0]); atomicAdd(&sg[6], a0[1]);
    if (special) { cor[ridx][0] = a0[0]; cor[ridx][1] = a0[1]; }
  }
  if (q == 3) {                                          // cols 62,63
    atomicAdd(&sg[7], a3[2]); atomicAdd(&sg[8], a3[3]);
    if (special) { cor[ridx][2] = a3[2]; cor[ridx][3] = a3[3]; }
  }
  __syncthreads();

  if (t == 0) {
    const int EX[3][2] = {{2,3},{0,3},{0,1}};  // excluded indices per offset
    float T = sg[0];
    #pragma unroll
    for (int i = 0; i < 3; i++)
      #pragma unroll
      for (int j = 0; j < 3; j++) {
        float Re = sg[1 + EX[i][0]] + sg[1 + EX[i][1]];
        float Ce = sg[5 + EX[j][0]] + sg[5 + EX[j][1]];
        float Xc = cor[EX[i][0]][EX[j][0]] + cor[EX[i][0]][EX[j][1]]
                 + cor[EX[i][1]][EX[j][0]] + cor[EX[i][1]][EX[j][1]];
        sS[i * 3 + j] = T - Re - Ce + Xc;
      }
  }
  __syncthreads();

  if (t < EE) {
    const float* gw = gate_w + ((size_t)t * CC + c) * 9;
    float ge = 0.f;
    #pragma unroll
    for (int k = 0; k < 9; k++) ge += gw[k] * sS[k];
    int b = bc >> 6;
    gpart[b * (EE * CC) + t * CC + c] = ge;   // direct store, no atomic
  }
}

// ---------------------------------------------------------------------------
// Kernel B: gating reduce + softmax/top-1 + expert 1x1-conv mix, all fused.
// Block: (pt, b) = one batch, 128 pixels. LDS-staged bf16 W and X tiles.
// Thread: 8f x 4p register tile, c-loop in chunks of 4.
// ---------------------------------------------------------------------------
__global__ __launch_bounds__(256) void k_mix(
    const float* __restrict__ x, const float* __restrict__ expert_w,
    const float* __restrict__ gpart, const float* __restrict__ gate_b,
    float* __restrict__ out, float* __restrict__ ew_out) {
  __shared__ uint2 W2[64 * 16];   // bf16x4 per entry: [f][c/4]
  __shared__ uint2 X2[64 * 32];   // bf16x4 per entry: [c][px/4]
  __shared__ float gsh[EE];
  int t = threadIdx.x;
  int pt = blockIdx.x;            // 0..31 pixel tile
  int b  = blockIdx.y;

  // ---- X staging (independent of gating result) ----
  const float* Xg = x + (size_t)b * CC * HWX + pt * PXT;
  #pragma unroll
  for (int k = 0; k < 8; k++) {
    int idx = t + 256 * k;
    int r = idx >> 5, q = idx & 31;         // channel r, 4-px group q
    f4 v = *(const f4*)(Xg + (size_t)r * HWX + (q << 2));
    uint2 p; p.x = pack2(v[0], v[1]); p.y = pack2(v[2], v[3]);
    X2[r * 32 + q] = p;
  }

  // ---- gating reduction: 8 experts x 32 lanes ----
  {
    int e = t >> 5, j = t & 31;
    const float* gp = gpart + b * (EE * CC) + e * CC;
    float gval = gp[j] + gp[j + 32];
    #pragma unroll
    for (int off = 16; off > 0; off >>= 1) gval += __shfl_down(gval, off, 32);
    if (j == 0) gsh[e] = gval + 3844.0f * gate_b[e];
  }
  __syncthreads();

  // ---- every thread: top-1 softmax (block-uniform result) ----
  float g[EE];
  #pragma unroll
  for (int e = 0; e < EE; e++) g[e] = gsh[e];
  int best = 0; float bg = g[0];
  #pragma unroll
  for (int e = 1; e < EE; e++) if (g[e] > bg) { bg = g[e]; best = e; }
  float s = 0.f;
  #pragma unroll
  for (int e = 0; e < EE; e++) s += __expf(g[e] - bg);
  float sc = 1.0f / s;            // top-1 softmax prob
  if (pt == 0 && t < EE) ew_out[b * EE + t] = (t == best) ? sc : 0.f;

  // ---- W staging (needs `best`) ----
  const float* Wg = expert_w + (size_t)best * (CC * CC);
  #pragma unroll
  for (int k = 0; k < 4; k++) {
    int idx = t + 256 * k;
    int r = idx >> 4, q = idx & 15;         // out-ch r, 4-c group q
    f4 v = *(const f4*)(Wg + r * CC + (q << 2));
    uint2 p; p.x = pack2(v[0], v[1]); p.y = pack2(v[2], v[3]);
    W2[r * 16 + q] = p;
  }
  __syncthreads();

  // ---- inner product: 8f x 4p per thread over 64 c ----
  int f0 = (t >> 5) << 3;         // 0..56 step 8
  int px = t & 31;                // 4-px group; p0 = 4*px
  float acc[8][4] = {};
  #pragma unroll
  for (int cq = 0; cq < 16; cq++) {
    uint2 xu[4];
    #pragma unroll
    for (int j = 0; j < 4; j++) xu[j] = X2[((cq << 2) + j) * 32 + px];
    uint2 wu[8];
    #pragma unroll
    for (int i = 0; i < 8; i++) wu[i] = W2[(f0 + i) * 16 + cq];
    #pragma unroll
    for (int j = 0; j < 4; j++) {
      unsigned xr0 = xu[j].x, xr1 = xu[j].y;
      float xp0 = ubf_lo(xr0), xp1 = ubf_hi(xr0);
      float xp2 = ubf_lo(xr1), xp3 = ubf_hi(xr1);
      #pragma unroll
      for (int i = 0; i < 8; i++) {
        unsigned wraw = (j < 2) ? wu[i].x : wu[i].y;
        float wf = ((j & 1) == 0) ? ubf_lo(wraw) : ubf_hi(wraw);
        acc[i][0] += wf * xp0; acc[i][1] += wf * xp1;
        acc[i][2] += wf * xp2; acc[i][3] += wf * xp3;
      }
    }
  }

  // ---- scaled store ----
  float* Og = out + ((size_t)(b * CC + f0)) * HWX + pt * PXT + (px << 2);
  #pragma unroll
  for (int i = 0; i < 8; i++) {
    f4 r;
    r[0] = sc * acc[i][0]; r[1] = sc * acc[i][1];
    r[2] = sc * acc[i][2]; r[3] = sc * acc[i][3];
    *(f4*)(Og + (size_t)i * HWX) = r;
  }
}

// ---------------------------------------------------------------------------
extern "C" void kernel_launch(void* const* d_in, const int* in_sizes, int n_in,
                              void* d_out, int out_size, void* d_ws, size_t ws_size,
                              hipStream_t stream) {
  const float* x        = (const float*)d_in[0];   // [32,64,64,64]
  const float* gate_w   = (const float*)d_in[1];   // [8,64,3,3]
  const float* gate_b   = (const float*)d_in[2];   // [8]
  const float* expert_w = (const float*)d_in[3];   // [8,64,64]
  float* out = (float*)d_out;                      // [32,64,64,64] then [32,8]
  float* ew_out = out + (size_t)BB * CC * HWX;

  float* gpart = (float*)d_ws;   // [32][8][64] partials, fully written by kA

  k_gate_sums<<<BB * CC, 256, 0, stream>>>(x, gate_w, gpart);
  k_mix<<<dim3(HWX / PXT, BB), 256, 0, stream>>>(x, expert_w, gpart, gate_b,
                                                 out, ew_out);
}

// Round 3
// 102.774 us; speedup vs baseline: 1.0786x; 1.0786x over previous
//
#include <hip/hip_runtime.h>

typedef float f4 __attribute__((ext_vector_type(4)));
typedef short bf16x8 __attribute__((ext_vector_type(8)));
typedef float f32x4 __attribute__((ext_vector_type(4)));

#define BB 32
#define CC 64
#define EE 8
#define HWX 4096   // 64*64 pixels
#define PXT 128    // pixels per mix block

// ---------------------------------------------------------------------------
// bf16 round-to-nearest-even helpers
// ---------------------------------------------------------------------------
__device__ __forceinline__ unsigned bf16r(float f) {
  unsigned u = __builtin_bit_cast(unsigned, f);
  u += 0x7FFFu + ((u >> 16) & 1u);
  return u >> 16;
}
__device__ __forceinline__ unsigned pack2(float a, float b) {
  return bf16r(a) | (bf16r(b) << 16);
}

union frag_cast { bf16x8 v; unsigned u[4]; };

// ---------------------------------------------------------------------------
// Kernel A: per-(b,c) plane reductions -> per-c gating partials (no atomics)
// gpart[b][e][c] = sum_{i,j} gw[e,c,i,j] * S[b,c,i,j]
// S[i,j] = T - excludedRows(i) - excludedCols(j) + corners(i,j)
// ---------------------------------------------------------------------------
__global__ __launch_bounds__(256) void k_gate_sums(
    const float* __restrict__ x, const float* __restrict__ gate_w,
    float* __restrict__ gpart) {
  __shared__ float sg[9];       // [T, r0,r1,r62,r63, c0,c1,c62,c63]
  __shared__ float cor[4][4];   // corner cells, rows/cols in {0,1,62,63}
  __shared__ float sS[9];       // the 9 window sums S[i*3+j]
  int t = threadIdx.x;
  int bc = blockIdx.x;          // b*64 + c
  int c = bc & 63;
  const float* plane = x + (size_t)bc * HWX;
  int h = t >> 2, q = t & 3;    // row h (0..63), quarter q (16 floats each)
  const f4* rp = (const f4*)(plane + h * 64 + q * 16);
  f4 a0 = rp[0], a1 = rp[1], a2 = rp[2], a3 = rp[3];
  float local = (a0[0]+a0[1]+a0[2]+a0[3]) + (a1[0]+a1[1]+a1[2]+a1[3])
              + (a2[0]+a2[1]+a2[2]+a2[3]) + (a3[0]+a3[1]+a3[2]+a3[3]);
  if (t < 9) sg[t] = 0.f;
  __syncthreads();

  bool special = (h < 2) || (h >= 62);
  int ridx = (h < 2) ? h : h - 60;   // 0,1,62,63 -> 0,1,2,3

  // wave-reduce the total, one LDS atomic per wave
  float red = local;
  #pragma unroll
  for (int off = 32; off > 0; off >>= 1) red += __shfl_down(red, off, 64);
  if ((t & 63) == 0) atomicAdd(&sg[0], red);

  if (special) atomicAdd(&sg[1 + ridx], local);          // full-row sums
  if (q == 0) {                                          // cols 0,1
    atomicAdd(&sg[5], a0[0]); atomicAdd(&sg[6], a0[1]);
    if (special) { cor[ridx][0] = a0[0]; cor[ridx][1] = a0[1]; }
  }
  if (q == 3) {                                          // cols 62,63
    atomicAdd(&sg[7], a3[2]); atomicAdd(&sg[8], a3[3]);
    if (special) { cor[ridx][2] = a3[2]; cor[ridx][3] = a3[3]; }
  }
  __syncthreads();

  if (t == 0) {
    const int EX[3][2] = {{2,3},{0,3},{0,1}};  // excluded indices per offset
    float T = sg[0];
    #pragma unroll
    for (int i = 0; i < 3; i++)
      #pragma unroll
      for (int j = 0; j < 3; j++) {
        float Re = sg[1 + EX[i][0]] + sg[1 + EX[i][1]];
        float Ce = sg[5 + EX[j][0]] + sg[5 + EX[j][1]];
        float Xc = cor[EX[i][0]][EX[j][0]] + cor[EX[i][0]][EX[j][1]]
                 + cor[EX[i][1]][EX[j][0]] + cor[EX[i][1]][EX[j][1]];
        sS[i * 3 + j] = T - Re - Ce + Xc;
      }
  }
  __syncthreads();

  if (t < EE) {
    const float* gw = gate_w + ((size_t)t * CC + c) * 9;
    float ge = 0.f;
    #pragma unroll
    for (int k = 0; k < 9; k++) ge += gw[k] * sS[k];
    int b = bc >> 6;
    gpart[b * (EE * CC) + t * CC + c] = ge;   // direct store, no atomic
  }
}

// ---------------------------------------------------------------------------
// Kernel B: gating reduce + softmax/top-1 + MFMA expert 1x1-conv mix.
// Block: (pt, b) = one batch, 128 px. 4 waves; wave w owns px [32w, 32w+32).
// No LDS tiles: A-frags (W) and B-frags (x) load straight from global,
// converted to bf16 in regs; 16 mfma_f32_16x16x32_bf16 per wave.
// MFMA layouts (HW-verified m89/m91/m120):
//   A[m=lane&15][k=quad*8+j], B[k=quad*8+j][n=lane&15],
//   D: col(n)=lane&15, row(m)=quad*4+reg.
// ---------------------------------------------------------------------------
__global__ __launch_bounds__(256) void k_mix(
    const float* __restrict__ x, const float* __restrict__ expert_w,
    const float* __restrict__ gpart, const float* __restrict__ gate_b,
    float* __restrict__ out, float* __restrict__ ew_out) {
  __shared__ float gsh[EE];
  int t = threadIdx.x;
  int pt = blockIdx.x;            // 0..31 pixel tile (128 px)
  int b  = blockIdx.y;

  // ---- gating reduction: 8 experts x 32 lanes ----
  {
    int e = t >> 5, j = t & 31;
    const float* gp = gpart + b * (EE * CC) + e * CC;
    float gval = gp[j] + gp[j + 32];
    #pragma unroll
    for (int off = 16; off > 0; off >>= 1) gval += __shfl_down(gval, off, 32);
    if (j == 0) gsh[e] = gval + 3844.0f * gate_b[e];
  }
  __syncthreads();

  // ---- every thread: top-1 softmax (block-uniform result) ----
  float g[EE];
  #pragma unroll
  for (int e = 0; e < EE; e++) g[e] = gsh[e];
  int best = 0; float bg = g[0];
  #pragma unroll
  for (int e = 1; e < EE; e++) if (g[e] > bg) { bg = g[e]; best = e; }
  float s = 0.f;
  #pragma unroll
  for (int e = 0; e < EE; e++) s += __expf(g[e] - bg);
  float sc = 1.0f / s;            // top-1 softmax prob
  if (pt == 0 && t < EE) ew_out[b * EE + t] = (t == best) ? sc : 0.f;

  int wave = t >> 6;
  int lane = t & 63;
  int l15  = lane & 15;
  int quad = lane >> 4;

  // ---- A-frags: W[best][f0+l15][k0+quad*8+j], 4 f-tiles x 2 k0 ----
  const float* Wg = expert_w + (size_t)best * (CC * CC);
  bf16x8 afr[4][2];
  #pragma unroll
  for (int ft = 0; ft < 4; ft++) {
    const float* wrow = Wg + (ft * 16 + l15) * CC + quad * 8;
    #pragma unroll
    for (int kk = 0; kk < 2; kk++) {
      f4 w0 = *(const f4*)(wrow + kk * 32);
      f4 w1 = *(const f4*)(wrow + kk * 32 + 4);
      frag_cast fc;
      fc.u[0] = pack2(w0[0], w0[1]); fc.u[1] = pack2(w0[2], w0[3]);
      fc.u[2] = pack2(w1[0], w1[1]); fc.u[3] = pack2(w1[2], w1[3]);
      afr[ft][kk] = fc.v;
    }
  }

  // ---- B-frags + MFMA: wave owns px n0 = pt*128 + 32*wave + 16*s ----
  const float* Xb = x + (size_t)b * CC * HWX + pt * PXT + 32 * wave;
  f32x4 acc[2][4] = {};           // [s][ft]
  #pragma unroll
  for (int ss = 0; ss < 2; ss++) {
    const float* xp = Xb + ss * 16 + l15 + (size_t)(quad * 8) * HWX;
    #pragma unroll
    for (int kk = 0; kk < 2; kk++) {
      const float* xq = xp + (size_t)(kk * 32) * HWX;
      float e0 = xq[0];
      float e1 = xq[HWX];
      float e2 = xq[2 * HWX];
      float e3 = xq[3 * HWX];
      float e4 = xq[4 * HWX];
      float e5 = xq[5 * HWX];
      float e6 = xq[6 * HWX];
      float e7 = xq[7 * HWX];
      frag_cast fb;
      fb.u[0] = pack2(e0, e1); fb.u[1] = pack2(e2, e3);
      fb.u[2] = pack2(e4, e5); fb.u[3] = pack2(e6, e7);
      #pragma unroll
      for (int ft = 0; ft < 4; ft++)
        acc[ss][ft] = __builtin_amdgcn_mfma_f32_16x16x32_bf16(
            afr[ft][kk], fb.v, acc[ss][ft], 0, 0, 0);
    }
  }

  // ---- scaled store: f = 16*ft + quad*4 + r, px = pt*128+32w+16s+l15 ----
  #pragma unroll
  for (int ss = 0; ss < 2; ss++) {
    #pragma unroll
    for (int ft = 0; ft < 4; ft++) {
      int f = ft * 16 + quad * 4;
      float* Og = out + ((size_t)(b * CC + f)) * HWX
                + pt * PXT + 32 * wave + ss * 16 + l15;
      #pragma unroll
      for (int r = 0; r < 4; r++)
        Og[(size_t)r * HWX] = sc * acc[ss][ft][r];
    }
  }
}

// ---------------------------------------------------------------------------
extern "C" void kernel_launch(void* const* d_in, const int* in_sizes, int n_in,
                              void* d_out, int out_size, void* d_ws, size_t ws_size,
                              hipStream_t stream) {
  const float* x        = (const float*)d_in[0];   // [32,64,64,64]
  const float* gate_w   = (const float*)d_in[1];   // [8,64,3,3]
  const float* gate_b   = (const float*)d_in[2];   // [8]
  const float* expert_w = (const float*)d_in[3];   // [8,64,64]
  float* out = (float*)d_out;                      // [32,64,64,64] then [32,8]
  float* ew_out = out + (size_t)BB * CC * HWX;

  float* gpart = (float*)d_ws;   // [32][8][64] partials, fully written by kA

  k_gate_sums<<<BB * CC, 256, 0, stream>>>(x, gate_w, gpart);
  k_mix<<<dim3(HWX / PXT, BB), 256, 0, stream>>>(x, expert_w, gpart, gate_b,
                                                 out, ew_out);
}